// Round 6
// baseline (2587.265 us; speedup 1.0000x reference)
//
#include <hip/hip_runtime.h>
#include <math.h>

#define TOTAL  65536      // B*2*N nodes
#define NDIM   128        // D
#define NEDGE  524288     // E
#define EDIM   64         // ED

typedef __bf16 bf16x8 __attribute__((ext_vector_type(8)));
typedef float  f32x4  __attribute__((ext_vector_type(4)));
typedef unsigned int u32x4 __attribute__((ext_vector_type(4)));
typedef unsigned short u16x8 __attribute__((ext_vector_type(8)));

#define MFMA(a, b, c) __builtin_amdgcn_mfma_f32_16x16x32_bf16((a), (b), (c), 0, 0, 0)

static __device__ __forceinline__ float b2f(unsigned short u) {
    union { float f; unsigned int i; } v; v.i = ((unsigned int)u) << 16; return v.f;
}
static __device__ __forceinline__ unsigned short f2b(float f) {  // RNE
    union { float f; unsigned int i; } v; v.f = f;
    unsigned int r = v.i + 0x7FFFu + ((v.i >> 16) & 1u);
    return (unsigned short)(r >> 16);
}
static __device__ __forceinline__ bf16x8 ldfrag(const unsigned short* p) {
    return __builtin_bit_cast(bf16x8, *(const u32x4*)p);
}
static __device__ __forceinline__ bf16x8 packf8(float4 a, float4 b) {
    u32x4 u;
    u[0] = (unsigned int)f2b(a.x) | ((unsigned int)f2b(a.y) << 16);
    u[1] = (unsigned int)f2b(a.z) | ((unsigned int)f2b(a.w) << 16);
    u[2] = (unsigned int)f2b(b.x) | ((unsigned int)f2b(b.y) << 16);
    u[3] = (unsigned int)f2b(b.z) | ((unsigned int)f2b(b.w) << 16);
    return __builtin_bit_cast(bf16x8, u);
}

// ---------------------------------------------------------------------------
// cvt: fp32 -> bf16, vectorized
// ---------------------------------------------------------------------------
__global__ __launch_bounds__(256) void cvt_kernel(
    const float* __restrict__ in, unsigned short* __restrict__ out, int n4)
{
    int i = blockIdx.x * 256 + threadIdx.x;
    if (i < n4) {
        float4 x = *(const float4*)&in[(size_t)i * 4];
        out[(size_t)i * 4 + 0] = f2b(x.x);
        out[(size_t)i * 4 + 1] = f2b(x.y);
        out[(size_t)i * 4 + 2] = f2b(x.z);
        out[(size_t)i * 4 + 3] = f2b(x.w);
    }
}

// transpose fp32 [K][N] -> bf16 [N][K]
__global__ __launch_bounds__(256) void tk_kernel(
    const float* __restrict__ src, unsigned short* __restrict__ dst, int K, int N)
{
    int idx = blockIdx.x * 256 + threadIdx.x;
    if (idx < N * K) {
        int n = idx / K, k = idx - n * K;
        dst[idx] = f2b(src[(size_t)k * N + n]);
    }
}

// ---------------------------------------------------------------------------
// edge (MFMA, fused msg_in): A = [ns[src] | ns[dst] | ef]  (K = 320)
// Block = 64 edges, 4 waves; wave w owns edges w*16..w*16+15 (rows = lr).
// No LDS A-staging; h tiles live in wave-private LDS bands (no barriers).
// Scatter from C-fragments with fp32 atomics.
// ---------------------------------------------------------------------------
__global__ __launch_bounds__(256) void edge_mfma(
    const unsigned short* __restrict__ ns,
    const float* __restrict__ ef, const int* __restrict__ ev,
    const unsigned short* __restrict__ w1T,  // [128][320]
    const unsigned short* __restrict__ w2T,  // [128][128]
    const unsigned short* __restrict__ w3T,  // [128][128]
    const float* __restrict__ b1, const float* __restrict__ b2,
    const float* __restrict__ b3, float* __restrict__ summed)
{
    __shared__ unsigned short s_h0[64 * 128];  // 16 KB
    __shared__ unsigned short s_h1[64 * 128];  // 16 KB
    __shared__ int s_src[64], s_dst[64];

    const int tid = threadIdx.x;
    const int w = tid >> 6, l = tid & 63;
    const int lr = l & 15, lg = l >> 4;
    const size_t eblk = (size_t)blockIdx.x * 64;

    if (tid < 128) {
        const int v = ev[eblk * 2 + tid];
        if (tid & 1) s_dst[tid >> 1] = v; else s_src[tid >> 1] = v;
    }
    __syncthreads();

    const int mye = w * 16 + lr;               // A-row (edge) for frag loads
    const int msrc = s_src[mye], mdst = s_dst[mye];
    const size_t erow = eblk + mye;

    f32x4 acc[8];
#pragma unroll
    for (int nb = 0; nb < 8; ++nb) {
        const float bv = b1[nb * 16 + lr];
        acc[nb] = (f32x4){bv, bv, bv, bv};
    }
    // ---- L1 seg0: ns[src], k = 0..127 ----
#pragma unroll
    for (int kb = 0; kb < 4; ++kb) {
        const bf16x8 af = ldfrag(&ns[(size_t)msrc * 128 + kb * 32 + lg * 8]);
#pragma unroll
        for (int nb = 0; nb < 8; ++nb)
            acc[nb] = MFMA(af, ldfrag(&w1T[(size_t)(nb * 16 + lr) * 320 + kb * 32 + lg * 8]), acc[nb]);
    }
    // ---- L1 seg1: ns[dst], k = 128..255 ----
#pragma unroll
    for (int kb = 0; kb < 4; ++kb) {
        const bf16x8 af = ldfrag(&ns[(size_t)mdst * 128 + kb * 32 + lg * 8]);
#pragma unroll
        for (int nb = 0; nb < 8; ++nb)
            acc[nb] = MFMA(af, ldfrag(&w1T[(size_t)(nb * 16 + lr) * 320 + 128 + kb * 32 + lg * 8]), acc[nb]);
    }
    // ---- L1 seg2: ef (cvt on the fly), k = 256..319 ----
#pragma unroll
    for (int kb = 0; kb < 2; ++kb) {
        const float4 x0 = *(const float4*)&ef[erow * EDIM + kb * 32 + lg * 8];
        const float4 x1 = *(const float4*)&ef[erow * EDIM + kb * 32 + lg * 8 + 4];
        const bf16x8 af = packf8(x0, x1);
#pragma unroll
        for (int nb = 0; nb < 8; ++nb)
            acc[nb] = MFMA(af, ldfrag(&w1T[(size_t)(nb * 16 + lr) * 320 + 256 + kb * 32 + lg * 8]), acc[nb]);
    }
    // relu -> s_h0 (wave-private rows, XOR swizzle)
#pragma unroll
    for (int nb = 0; nb < 8; ++nb)
#pragma unroll
        for (int r = 0; r < 4; ++r) {
            const int row = w * 16 + lg * 4 + r;
            const int us = (row * 128 + nb * 16 + lr) ^ ((row & 7) << 3);
            s_h0[us] = f2b(fmaxf(acc[nb][r], 0.f));
        }

    // ---- Layer 2: K = 128 ----
    const int asw = (mye & 7) << 3;
#pragma unroll
    for (int nb = 0; nb < 8; ++nb) {
        const float bv = b2[nb * 16 + lr];
        acc[nb] = (f32x4){bv, bv, bv, bv};
    }
#pragma unroll
    for (int kb = 0; kb < 4; ++kb) {
        const bf16x8 af = ldfrag(&s_h0[(mye * 128 + kb * 32 + lg * 8) ^ asw]);
#pragma unroll
        for (int nb = 0; nb < 8; ++nb)
            acc[nb] = MFMA(af, ldfrag(&w2T[(size_t)(nb * 16 + lr) * 128 + kb * 32 + lg * 8]), acc[nb]);
    }
#pragma unroll
    for (int nb = 0; nb < 8; ++nb)
#pragma unroll
        for (int r = 0; r < 4; ++r) {
            const int row = w * 16 + lg * 4 + r;
            const int us = (row * 128 + nb * 16 + lr) ^ ((row & 7) << 3);
            s_h1[us] = f2b(fmaxf(acc[nb][r], 0.f));
        }

    // ---- Layer 3: K = 128, no relu ----
#pragma unroll
    for (int nb = 0; nb < 8; ++nb) {
        const float bv = b3[nb * 16 + lr];
        acc[nb] = (f32x4){bv, bv, bv, bv};
    }
#pragma unroll
    for (int kb = 0; kb < 4; ++kb) {
        const bf16x8 af = ldfrag(&s_h1[(mye * 128 + kb * 32 + lg * 8) ^ asw]);
#pragma unroll
        for (int nb = 0; nb < 8; ++nb)
            acc[nb] = MFMA(af, ldfrag(&w3T[(size_t)(nb * 16 + lr) * 128 + kb * 32 + lg * 8]), acc[nb]);
    }

    // ---- scatter from C-fragments ----
#pragma unroll
    for (int r = 0; r < 4; ++r) {
        const int e = w * 16 + lg * 4 + r;
        const size_t sb = (size_t)s_src[e] * NDIM, db = (size_t)s_dst[e] * NDIM;
#pragma unroll
        for (int nb = 0; nb < 8; ++nb) {
            const float v = acc[nb][r];
            atomicAdd(&summed[sb + nb * 16 + lr], v);
            atomicAdd(&summed[db + nb * 16 + lr], v);
        }
    }
}

// ---------------------------------------------------------------------------
// upd (MFMA): A = [ns, summed, ns - partner] (K = 384); rows = consecutive
// nodes, per-lane global loads (no A-staging). h tiles wave-private.
// ---------------------------------------------------------------------------
__global__ __launch_bounds__(256) void upd_mfma(
    const unsigned short* __restrict__ ns, const float* __restrict__ summed,
    const unsigned short* __restrict__ u1T,  // [128][384]
    const unsigned short* __restrict__ u2T, const unsigned short* __restrict__ u3T,
    const float* __restrict__ ub1, const float* __restrict__ ub2,
    const float* __restrict__ ub3, unsigned short* __restrict__ out)
{
    __shared__ unsigned short s_h0[64 * 128];
    __shared__ unsigned short s_h1[64 * 128];

    const int tid = threadIdx.x;
    const int w = tid >> 6, l = tid & 63;
    const int lr = l & 15, lg = l >> 4;
    const int n0blk = blockIdx.x * 64;
    const int node = n0blk + w * 16 + lr;
    const int partner = node ^ 4096;

    bf16x8 nsf[4];
#pragma unroll
    for (int kb = 0; kb < 4; ++kb)
        nsf[kb] = ldfrag(&ns[(size_t)node * 128 + kb * 32 + lg * 8]);

    f32x4 acc[8];
#pragma unroll
    for (int nb = 0; nb < 8; ++nb) {
        const float bv = ub1[nb * 16 + lr];
        acc[nb] = (f32x4){bv, bv, bv, bv};
    }
    // seg0: ns, k = 0..127
#pragma unroll
    for (int kb = 0; kb < 4; ++kb) {
#pragma unroll
        for (int nb = 0; nb < 8; ++nb)
            acc[nb] = MFMA(nsf[kb], ldfrag(&u1T[(size_t)(nb * 16 + lr) * 384 + kb * 32 + lg * 8]), acc[nb]);
    }
    // seg1: summed (fp32 -> bf16), k = 128..255
#pragma unroll
    for (int kb = 0; kb < 4; ++kb) {
        const float4 x0 = *(const float4*)&summed[(size_t)node * 128 + kb * 32 + lg * 8];
        const float4 x1 = *(const float4*)&summed[(size_t)node * 128 + kb * 32 + lg * 8 + 4];
        const bf16x8 af = packf8(x0, x1);
#pragma unroll
        for (int nb = 0; nb < 8; ++nb)
            acc[nb] = MFMA(af, ldfrag(&u1T[(size_t)(nb * 16 + lr) * 384 + 128 + kb * 32 + lg * 8]), acc[nb]);
    }
    // seg2: att = ns - ns[partner], k = 256..383
#pragma unroll
    for (int kb = 0; kb < 4; ++kb) {
        const u16x8 a = __builtin_bit_cast(u16x8, nsf[kb]);
        const u16x8 p = __builtin_bit_cast(u16x8, ldfrag(&ns[(size_t)partner * 128 + kb * 32 + lg * 8]));
        u16x8 o;
#pragma unroll
        for (int i = 0; i < 8; ++i) o[i] = f2b(b2f(a[i]) - b2f(p[i]));
        const bf16x8 af = __builtin_bit_cast(bf16x8, o);
#pragma unroll
        for (int nb = 0; nb < 8; ++nb)
            acc[nb] = MFMA(af, ldfrag(&u1T[(size_t)(nb * 16 + lr) * 384 + 256 + kb * 32 + lg * 8]), acc[nb]);
    }
#pragma unroll
    for (int nb = 0; nb < 8; ++nb)
#pragma unroll
        for (int r = 0; r < 4; ++r) {
            const int row = w * 16 + lg * 4 + r;
            const int us = (row * 128 + nb * 16 + lr) ^ ((row & 7) << 3);
            s_h0[us] = f2b(fmaxf(acc[nb][r], 0.f));
        }

    // ---- Layer 2 ----
    const int myrow = w * 16 + lr;
    const int asw = (myrow & 7) << 3;
#pragma unroll
    for (int nb = 0; nb < 8; ++nb) {
        const float bv = ub2[nb * 16 + lr];
        acc[nb] = (f32x4){bv, bv, bv, bv};
    }
#pragma unroll
    for (int kb = 0; kb < 4; ++kb) {
        const bf16x8 af = ldfrag(&s_h0[(myrow * 128 + kb * 32 + lg * 8) ^ asw]);
#pragma unroll
        for (int nb = 0; nb < 8; ++nb)
            acc[nb] = MFMA(af, ldfrag(&u2T[(size_t)(nb * 16 + lr) * 128 + kb * 32 + lg * 8]), acc[nb]);
    }
#pragma unroll
    for (int nb = 0; nb < 8; ++nb)
#pragma unroll
        for (int r = 0; r < 4; ++r) {
            const int row = w * 16 + lg * 4 + r;
            const int us = (row * 128 + nb * 16 + lr) ^ ((row & 7) << 3);
            s_h1[us] = f2b(fmaxf(acc[nb][r], 0.f));
        }

    // ---- Layer 3 ----
#pragma unroll
    for (int nb = 0; nb < 8; ++nb) {
        const float bv = ub3[nb * 16 + lr];
        acc[nb] = (f32x4){bv, bv, bv, bv};
    }
#pragma unroll
    for (int kb = 0; kb < 4; ++kb) {
        const bf16x8 af = ldfrag(&s_h1[(myrow * 128 + kb * 32 + lg * 8) ^ asw]);
#pragma unroll
        for (int nb = 0; nb < 8; ++nb)
            acc[nb] = MFMA(af, ldfrag(&u3T[(size_t)(nb * 16 + lr) * 128 + kb * 32 + lg * 8]), acc[nb]);
    }
#pragma unroll
    for (int nb = 0; nb < 8; ++nb)
#pragma unroll
        for (int r = 0; r < 4; ++r)
            out[(size_t)(n0blk + w * 16 + lg * 4 + r) * NDIM + nb * 16 + lr] = f2b(acc[nb][r]);
}

// ---------------------------------------------------------------------------
// gate + per-graph reduction (VALU, bf16 node states)
// ---------------------------------------------------------------------------
#define GPB 8
__global__ __launch_bounds__(128) void gate_kernel(
    const unsigned short* __restrict__ ns, const float* __restrict__ gw,
    const float* __restrict__ gb, float* __restrict__ gs)
{
    __shared__ float s_x[GPB][NDIM];
    const int j = threadIdx.x;
    const int n0 = blockIdx.x * GPB;
#pragma unroll
    for (int r = 0; r < GPB; ++r)
        s_x[r][j] = b2f(ns[(size_t)(n0 + r) * NDIM + j]);
    __syncthreads();

    float acc[GPB];
    const float bb = gb[j];
#pragma unroll
    for (int r = 0; r < GPB; ++r) acc[r] = bb;
    for (int i = 0; i < NDIM; i += 4) {
        const float w0 = gw[(i + 0) * NDIM + j];
        const float w1 = gw[(i + 1) * NDIM + j];
        const float wv2 = gw[(i + 2) * NDIM + j];
        const float wv3 = gw[(i + 3) * NDIM + j];
#pragma unroll
        for (int r = 0; r < GPB; ++r) {
            const float4 x = *(const float4*)&s_x[r][i];
            acc[r] = fmaf(x.x, w0, acc[r]);
            acc[r] = fmaf(x.y, w1, acc[r]);
            acc[r] = fmaf(x.z, wv2, acc[r]);
            acc[r] = fmaf(x.w, wv3, acc[r]);
        }
    }
    float part = 0.f;
#pragma unroll
    for (int r = 0; r < GPB; ++r) {
        const float g = 1.f / (1.f + expf(-acc[r]));
        part += s_x[r][j] * g;
    }
    atomicAdd(&gs[(n0 >> 12) * NDIM + j], part);
}

// ---------------------------------------------------------------------------
// final: out = relu(gs @ agg_w1 + ab1) @ agg_w2 + ab2    (16x128 -> 16x128)
// ---------------------------------------------------------------------------
__global__ __launch_bounds__(256) void final_kernel(
    const float* __restrict__ gs,
    const float* __restrict__ aw1, const float* __restrict__ ab1,
    const float* __restrict__ aw2, const float* __restrict__ ab2,
    float* __restrict__ out)
{
    __shared__ float s_g[16 * 128];
    __shared__ float s_h[16 * 256];
    const int t = threadIdx.x;
    for (int k = t; k < 16 * 128; k += 256) s_g[k] = gs[k];
    __syncthreads();
    for (int r = 0; r < 16; ++r) {
        float a = ab1[t];
        for (int i = 0; i < 128; ++i)
            a = fmaf(s_g[r * 128 + i], aw1[i * 256 + t], a);
        s_h[r * 256 + t] = fmaxf(a, 0.f);
    }
    __syncthreads();
    for (int k = t; k < 16 * 128; k += 256) {
        const int r = k >> 7, j = k & 127;
        float a = ab2[j];
        for (int i = 0; i < 256; ++i)
            a = fmaf(s_h[r * 256 + i], aw2[i * 128 + j], a);
        out[k] = a;
    }
}

// ---------------------------------------------------------------------------
extern "C" void kernel_launch(void* const* d_in, const int* in_sizes, int n_in,
                              void* d_out, int out_size, void* d_ws, size_t ws_size,
                              hipStream_t stream)
{
    const float* nf      = (const float*)d_in[0];
    const float* ef      = (const float*)d_in[1];
    const int*   ev      = (const int*)d_in[2];
    const float* msg_w1  = (const float*)d_in[3];
    const float* msg_b1  = (const float*)d_in[4];
    const float* msg_w2  = (const float*)d_in[5];
    const float* msg_b2  = (const float*)d_in[6];
    const float* msg_w3  = (const float*)d_in[7];
    const float* msg_b3  = (const float*)d_in[8];
    const float* upd_w1  = (const float*)d_in[9];
    const float* upd_b1  = (const float*)d_in[10];
    const float* upd_w2  = (const float*)d_in[11];
    const float* upd_b2  = (const float*)d_in[12];
    const float* upd_w3  = (const float*)d_in[13];
    const float* upd_b3  = (const float*)d_in[14];
    const float* gate_w  = (const float*)d_in[15];
    const float* gate_b  = (const float*)d_in[16];
    const float* agg_w1  = (const float*)d_in[17];
    const float* agg_b1  = (const float*)d_in[18];
    const float* agg_w2  = (const float*)d_in[19];
    const float* agg_b2  = (const float*)d_in[20];

    const size_t NS = (size_t)TOTAL * NDIM;
    unsigned short* ns0 = (unsigned short*)d_ws;
    unsigned short* nsA = ns0 + NS;
    unsigned short* nsB = nsA + NS;
    float* summed = (float*)(nsB + NS);
    float* gs     = summed + NS;
    unsigned short* w1T = (unsigned short*)(gs + 16 * NDIM);   // [128][320]
    unsigned short* w2T = w1T + 128 * 320;
    unsigned short* w3T = w2T + 128 * 128;
    unsigned short* u1T = w3T + 128 * 128;                     // [128][384]
    unsigned short* u2T = u1T + 128 * 384;
    unsigned short* u3T = u2T + 128 * 128;

    cvt_kernel<<<(int)(NS / 4 + 255) / 256, 256, 0, stream>>>(nf, ns0, (int)(NS / 4));
    tk_kernel<<<(320 * 128 + 255) / 256, 256, 0, stream>>>(msg_w1, w1T, 320, 128);
    tk_kernel<<<(128 * 128 + 255) / 256, 256, 0, stream>>>(msg_w2, w2T, 128, 128);
    tk_kernel<<<(128 * 128 + 255) / 256, 256, 0, stream>>>(msg_w3, w3T, 128, 128);
    tk_kernel<<<(384 * 128 + 255) / 256, 256, 0, stream>>>(upd_w1, u1T, 384, 128);
    tk_kernel<<<(128 * 128 + 255) / 256, 256, 0, stream>>>(upd_w2, u2T, 128, 128);
    tk_kernel<<<(128 * 128 + 255) / 256, 256, 0, stream>>>(upd_w3, u3T, 128, 128);

    const unsigned short* curs[3] = { ns0, nsA, nsB };
    unsigned short* nxts[3]       = { nsA, nsB, nsA };
    for (int lyr = 0; lyr < 3; ++lyr) {
        hipMemsetAsync(summed, 0, NS * sizeof(float), stream);
        edge_mfma<<<NEDGE / 64, 256, 0, stream>>>(curs[lyr], ef, ev, w1T, w2T, w3T,
                                                  msg_b1, msg_b2, msg_b3, summed);
        upd_mfma<<<TOTAL / 64, 256, 0, stream>>>(curs[lyr], summed, u1T, u2T, u3T,
                                                 upd_b1, upd_b2, upd_b3, nxts[lyr]);
    }
    hipMemsetAsync(gs, 0, (size_t)16 * NDIM * sizeof(float), stream);
    gate_kernel<<<TOTAL / GPB, 128, 0, stream>>>(nsA, gate_w, gate_b, gs);
    final_kernel<<<1, 256, 0, stream>>>(gs, agg_w1, agg_b1, agg_w2, agg_b2,
                                        (float*)d_out);
}

// Round 7
// 2120.708 us; speedup vs baseline: 1.2200x; 1.2200x over previous
//
#include <hip/hip_runtime.h>
#include <math.h>

#define TOTAL  65536      // B*2*N nodes
#define NDIM   128        // D
#define NEDGE  524288     // E
#define EDIM   64         // ED

typedef __bf16 bf16x8 __attribute__((ext_vector_type(8)));
typedef float  f32x4  __attribute__((ext_vector_type(4)));
typedef unsigned int u32x4 __attribute__((ext_vector_type(4)));
typedef unsigned short u16x8 __attribute__((ext_vector_type(8)));

#define MFMA(a, b, c) __builtin_amdgcn_mfma_f32_16x16x32_bf16((a), (b), (c), 0, 0, 0)

static __device__ __forceinline__ float b2f(unsigned short u) {
    union { float f; unsigned int i; } v; v.i = ((unsigned int)u) << 16; return v.f;
}
static __device__ __forceinline__ unsigned short f2b(float f) {  // RNE
    union { float f; unsigned int i; } v; v.f = f;
    unsigned int r = v.i + 0x7FFFu + ((v.i >> 16) & 1u);
    return (unsigned short)(r >> 16);
}
static __device__ __forceinline__ bf16x8 ldfrag(const unsigned short* p) {
    return __builtin_bit_cast(bf16x8, *(const u32x4*)p);
}
static __device__ __forceinline__ bf16x8 packf8(float4 a, float4 b) {
    u32x4 u;
    u[0] = (unsigned int)f2b(a.x) | ((unsigned int)f2b(a.y) << 16);
    u[1] = (unsigned int)f2b(a.z) | ((unsigned int)f2b(a.w) << 16);
    u[2] = (unsigned int)f2b(b.x) | ((unsigned int)f2b(b.y) << 16);
    u[3] = (unsigned int)f2b(b.z) | ((unsigned int)f2b(b.w) << 16);
    return __builtin_bit_cast(bf16x8, u);
}

// ---------------------------------------------------------------------------
// cvt: fp32 -> bf16 (node features)
// ---------------------------------------------------------------------------
__global__ __launch_bounds__(256) void cvt_kernel(
    const float* __restrict__ in, unsigned short* __restrict__ out, int n4)
{
    int i = blockIdx.x * 256 + threadIdx.x;
    if (i < n4) {
        float4 x = *(const float4*)&in[(size_t)i * 4];
        out[(size_t)i * 4 + 0] = f2b(x.x);
        out[(size_t)i * 4 + 1] = f2b(x.y);
        out[(size_t)i * 4 + 2] = f2b(x.z);
        out[(size_t)i * 4 + 3] = f2b(x.w);
    }
}

// ---------------------------------------------------------------------------
// pk_w: pack fp32 weight [K][128] -> frag-major bf16 [KB][8][64][8]
// dst[(((kb*8+nb)*64+l)*8)+j] = W[kb*32+(l>>4)*8+j][nb*16+(l&15)]
// A wave's B-frag load becomes one contiguous 1KB transaction.
// ---------------------------------------------------------------------------
__global__ __launch_bounds__(256) void pkw_kernel(
    const float* __restrict__ src, unsigned short* __restrict__ dst, int KB)
{
    int idx = blockIdx.x * 256 + threadIdx.x;
    if (idx >= KB * 4096) return;
    const int j  = idx & 7;
    const int l  = (idx >> 3) & 63;
    const int nb = (idx >> 9) & 7;
    const int kb = idx >> 12;
    const int k   = kb * 32 + (l >> 4) * 8 + j;
    const int col = nb * 16 + (l & 15);
    dst[idx] = f2b(src[(size_t)k * 128 + col]);
}

// ---------------------------------------------------------------------------
// pkef: pack edge features fp32 [E][64] -> bf16 frag-major
// idx = ((((blk*4+w)*2+rt)*2+kb)*64+l)*8+j ; e = blk*128+w*32+rt*16+(l&15)
// col = kb*32+(l>>4)*8+j
// ---------------------------------------------------------------------------
__global__ __launch_bounds__(256) void pkef_kernel(
    const float* __restrict__ ef, unsigned short* __restrict__ out)
{
    const size_t idx = (size_t)blockIdx.x * 256 + threadIdx.x;  // < E*64
    const int j  = (int)(idx & 7);
    const int l  = (int)((idx >> 3) & 63);
    const int kb = (int)((idx >> 9) & 1);
    const int rt = (int)((idx >> 10) & 1);
    const int w  = (int)((idx >> 11) & 3);
    const size_t blk = idx >> 13;
    const size_t e = blk * 128 + w * 32 + rt * 16 + (l & 15);
    const int col = kb * 32 + (l >> 4) * 8 + j;
    out[idx] = f2b(ef[e * 64 + col]);
}

// ---------------------------------------------------------------------------
// edge (MFMA): A = [ns[src] | ns[dst] | ef] (K=320), 3-layer MLP, scatter.
// Block = 128 edges, 4 waves; wave w owns 32 edges (two 16-row tiles).
// B-frags: frag-major coalesced. h: single reused wave-private LDS buffer
// (same-wave DS ops are in-order; all reads of layer k precede writes of k+1).
// ---------------------------------------------------------------------------
__global__ __launch_bounds__(256) void edge_mfma(
    const unsigned short* __restrict__ ns,
    const unsigned short* __restrict__ efp, const int* __restrict__ ev,
    const unsigned short* __restrict__ w1f,  // [10][8][64][8]
    const unsigned short* __restrict__ w2f,  // [4][8][64][8]
    const unsigned short* __restrict__ w3f,  // [4][8][64][8]
    const float* __restrict__ b1, const float* __restrict__ b2,
    const float* __restrict__ b3, float* __restrict__ summed)
{
    __shared__ unsigned short s_h[128 * 128];  // 32 KB, reused across layers
    __shared__ int s_src[128], s_dst[128];

    const int tid = threadIdx.x;
    const int w = tid >> 6, l = tid & 63;
    const int lr = l & 15, lg = l >> 4;
    const size_t eblk = (size_t)blockIdx.x * 128;

    {
        const int v = ev[eblk * 2 + tid];
        if (tid & 1) s_dst[tid >> 1] = v; else s_src[tid >> 1] = v;
    }
    __syncthreads();

    const int row0 = w * 32 + lr;      // A-row, tile rt=0
    const int row1 = row0 + 16;        // rt=1
    const int ms0 = s_src[row0], ms1 = s_src[row1];
    const int md0 = s_dst[row0], md1 = s_dst[row1];

    f32x4 acc0[8], acc1[8];
#pragma unroll
    for (int nb = 0; nb < 8; ++nb) {
        const float bv = b1[nb * 16 + lr];
        acc0[nb] = (f32x4){bv, bv, bv, bv};
        acc1[nb] = acc0[nb];
    }
    // ---- L1 seg0: ns[src], k=0..127 (w1f kb 0..3) ----
#pragma unroll
    for (int kb = 0; kb < 4; ++kb) {
        const bf16x8 a0 = ldfrag(&ns[(size_t)ms0 * 128 + kb * 32 + lg * 8]);
        const bf16x8 a1 = ldfrag(&ns[(size_t)ms1 * 128 + kb * 32 + lg * 8]);
#pragma unroll
        for (int nb = 0; nb < 8; ++nb) {
            const bf16x8 bfr = ldfrag(&w1f[(size_t)((kb * 8 + nb) * 64 + l) * 8]);
            acc0[nb] = MFMA(a0, bfr, acc0[nb]);
            acc1[nb] = MFMA(a1, bfr, acc1[nb]);
        }
    }
    // ---- L1 seg1: ns[dst], k=128..255 (w1f kb 4..7) ----
#pragma unroll
    for (int kb = 0; kb < 4; ++kb) {
        const bf16x8 a0 = ldfrag(&ns[(size_t)md0 * 128 + kb * 32 + lg * 8]);
        const bf16x8 a1 = ldfrag(&ns[(size_t)md1 * 128 + kb * 32 + lg * 8]);
#pragma unroll
        for (int nb = 0; nb < 8; ++nb) {
            const bf16x8 bfr = ldfrag(&w1f[(size_t)(((kb + 4) * 8 + nb) * 64 + l) * 8]);
            acc0[nb] = MFMA(a0, bfr, acc0[nb]);
            acc1[nb] = MFMA(a1, bfr, acc1[nb]);
        }
    }
    // ---- L1 seg2: packed ef, k=256..319 (w1f kb 8..9) ----
#pragma unroll
    for (int kb = 0; kb < 2; ++kb) {
        const size_t eb = (((size_t)blockIdx.x * 4 + w) * 4 + kb) * 512 + l * 8;
        const bf16x8 a0 = ldfrag(&efp[eb]);           // rt=0
        const bf16x8 a1 = ldfrag(&efp[eb + 1024]);    // rt=1
#pragma unroll
        for (int nb = 0; nb < 8; ++nb) {
            const bf16x8 bfr = ldfrag(&w1f[(size_t)(((kb + 8) * 8 + nb) * 64 + l) * 8]);
            acc0[nb] = MFMA(a0, bfr, acc0[nb]);
            acc1[nb] = MFMA(a1, bfr, acc1[nb]);
        }
    }
    // relu -> s_h (wave-private rows, XOR swizzle)
#pragma unroll
    for (int nb = 0; nb < 8; ++nb)
#pragma unroll
        for (int r = 0; r < 4; ++r) {
            const int ra = w * 32 + lg * 4 + r, rb = ra + 16;
            s_h[(ra * 128 + nb * 16 + lr) ^ ((ra & 7) << 3)] = f2b(fmaxf(acc0[nb][r], 0.f));
            s_h[(rb * 128 + nb * 16 + lr) ^ ((rb & 7) << 3)] = f2b(fmaxf(acc1[nb][r], 0.f));
        }

    const int sw0 = (row0 & 7) << 3, sw1 = (row1 & 7) << 3;
    // ---- Layer 2 ----
#pragma unroll
    for (int nb = 0; nb < 8; ++nb) {
        const float bv = b2[nb * 16 + lr];
        acc0[nb] = (f32x4){bv, bv, bv, bv};
        acc1[nb] = acc0[nb];
    }
#pragma unroll
    for (int kb = 0; kb < 4; ++kb) {
        const bf16x8 a0 = ldfrag(&s_h[(row0 * 128 + kb * 32 + lg * 8) ^ sw0]);
        const bf16x8 a1 = ldfrag(&s_h[(row1 * 128 + kb * 32 + lg * 8) ^ sw1]);
#pragma unroll
        for (int nb = 0; nb < 8; ++nb) {
            const bf16x8 bfr = ldfrag(&w2f[(size_t)((kb * 8 + nb) * 64 + l) * 8]);
            acc0[nb] = MFMA(a0, bfr, acc0[nb]);
            acc1[nb] = MFMA(a1, bfr, acc1[nb]);
        }
    }
#pragma unroll
    for (int nb = 0; nb < 8; ++nb)
#pragma unroll
        for (int r = 0; r < 4; ++r) {
            const int ra = w * 32 + lg * 4 + r, rb = ra + 16;
            s_h[(ra * 128 + nb * 16 + lr) ^ ((ra & 7) << 3)] = f2b(fmaxf(acc0[nb][r], 0.f));
            s_h[(rb * 128 + nb * 16 + lr) ^ ((rb & 7) << 3)] = f2b(fmaxf(acc1[nb][r], 0.f));
        }

    // ---- Layer 3 (no relu) ----
#pragma unroll
    for (int nb = 0; nb < 8; ++nb) {
        const float bv = b3[nb * 16 + lr];
        acc0[nb] = (f32x4){bv, bv, bv, bv};
        acc1[nb] = acc0[nb];
    }
#pragma unroll
    for (int kb = 0; kb < 4; ++kb) {
        const bf16x8 a0 = ldfrag(&s_h[(row0 * 128 + kb * 32 + lg * 8) ^ sw0]);
        const bf16x8 a1 = ldfrag(&s_h[(row1 * 128 + kb * 32 + lg * 8) ^ sw1]);
#pragma unroll
        for (int nb = 0; nb < 8; ++nb) {
            const bf16x8 bfr = ldfrag(&w3f[(size_t)((kb * 8 + nb) * 64 + l) * 8]);
            acc0[nb] = MFMA(a0, bfr, acc0[nb]);
            acc1[nb] = MFMA(a1, bfr, acc1[nb]);
        }
    }

    // ---- scatter from C-fragments ----
#pragma unroll
    for (int r = 0; r < 4; ++r) {
        const int ea = w * 32 + lg * 4 + r, eb2 = ea + 16;
        const size_t sa = (size_t)s_src[ea] * NDIM, da = (size_t)s_dst[ea] * NDIM;
        const size_t sb = (size_t)s_src[eb2] * NDIM, db = (size_t)s_dst[eb2] * NDIM;
#pragma unroll
        for (int nb = 0; nb < 8; ++nb) {
            const int col = nb * 16 + lr;
            const float v0 = acc0[nb][r], v1 = acc1[nb][r];
            atomicAdd(&summed[sa + col], v0);
            atomicAdd(&summed[da + col], v0);
            atomicAdd(&summed[sb + col], v1);
            atomicAdd(&summed[db + col], v1);
        }
    }
}

// ---------------------------------------------------------------------------
// upd (MFMA): A = [ns, summed, ns - partner] (K=384); 64 nodes/block, 4 waves.
// Frag-major weights; single reused 16KB h buffer (wave-private rows).
// ---------------------------------------------------------------------------
__global__ __launch_bounds__(256) void upd_mfma(
    const unsigned short* __restrict__ ns, const float* __restrict__ summed,
    const unsigned short* __restrict__ u1f,  // [12][8][64][8]
    const unsigned short* __restrict__ u2f, const unsigned short* __restrict__ u3f,
    const float* __restrict__ ub1, const float* __restrict__ ub2,
    const float* __restrict__ ub3, unsigned short* __restrict__ out)
{
    __shared__ unsigned short s_h[64 * 128];  // 16 KB, reused

    const int tid = threadIdx.x;
    const int w = tid >> 6, l = tid & 63;
    const int lr = l & 15, lg = l >> 4;
    const int n0blk = blockIdx.x * 64;
    const int node = n0blk + w * 16 + lr;
    const int partner = node ^ 4096;

    bf16x8 nsf[4];
#pragma unroll
    for (int kb = 0; kb < 4; ++kb)
        nsf[kb] = ldfrag(&ns[(size_t)node * 128 + kb * 32 + lg * 8]);

    f32x4 acc[8];
#pragma unroll
    for (int nb = 0; nb < 8; ++nb) {
        const float bv = ub1[nb * 16 + lr];
        acc[nb] = (f32x4){bv, bv, bv, bv};
    }
    // seg0: ns (u1f kb 0..3)
#pragma unroll
    for (int kb = 0; kb < 4; ++kb) {
#pragma unroll
        for (int nb = 0; nb < 8; ++nb)
            acc[nb] = MFMA(nsf[kb], ldfrag(&u1f[(size_t)((kb * 8 + nb) * 64 + l) * 8]), acc[nb]);
    }
    // seg1: summed fp32->bf16 (u1f kb 4..7)
#pragma unroll
    for (int kb = 0; kb < 4; ++kb) {
        const float4 x0 = *(const float4*)&summed[(size_t)node * 128 + kb * 32 + lg * 8];
        const float4 x1 = *(const float4*)&summed[(size_t)node * 128 + kb * 32 + lg * 8 + 4];
        const bf16x8 af = packf8(x0, x1);
#pragma unroll
        for (int nb = 0; nb < 8; ++nb)
            acc[nb] = MFMA(af, ldfrag(&u1f[(size_t)(((kb + 4) * 8 + nb) * 64 + l) * 8]), acc[nb]);
    }
    // seg2: att = ns - ns[partner] (u1f kb 8..11)
#pragma unroll
    for (int kb = 0; kb < 4; ++kb) {
        const u16x8 a = __builtin_bit_cast(u16x8, nsf[kb]);
        const u16x8 p = __builtin_bit_cast(u16x8, ldfrag(&ns[(size_t)partner * 128 + kb * 32 + lg * 8]));
        u16x8 o;
#pragma unroll
        for (int i = 0; i < 8; ++i) o[i] = f2b(b2f(a[i]) - b2f(p[i]));
        const bf16x8 af = __builtin_bit_cast(bf16x8, o);
#pragma unroll
        for (int nb = 0; nb < 8; ++nb)
            acc[nb] = MFMA(af, ldfrag(&u1f[(size_t)(((kb + 8) * 8 + nb) * 64 + l) * 8]), acc[nb]);
    }
#pragma unroll
    for (int nb = 0; nb < 8; ++nb)
#pragma unroll
        for (int r = 0; r < 4; ++r) {
            const int row = w * 16 + lg * 4 + r;
            s_h[(row * 128 + nb * 16 + lr) ^ ((row & 7) << 3)] = f2b(fmaxf(acc[nb][r], 0.f));
        }

    // ---- Layer 2 ----
    const int myrow = w * 16 + lr;
    const int asw = (myrow & 7) << 3;
#pragma unroll
    for (int nb = 0; nb < 8; ++nb) {
        const float bv = ub2[nb * 16 + lr];
        acc[nb] = (f32x4){bv, bv, bv, bv};
    }
#pragma unroll
    for (int kb = 0; kb < 4; ++kb) {
        const bf16x8 af = ldfrag(&s_h[(myrow * 128 + kb * 32 + lg * 8) ^ asw]);
#pragma unroll
        for (int nb = 0; nb < 8; ++nb)
            acc[nb] = MFMA(af, ldfrag(&u2f[(size_t)((kb * 8 + nb) * 64 + l) * 8]), acc[nb]);
    }
#pragma unroll
    for (int nb = 0; nb < 8; ++nb)
#pragma unroll
        for (int r = 0; r < 4; ++r) {
            const int row = w * 16 + lg * 4 + r;
            s_h[(row * 128 + nb * 16 + lr) ^ ((row & 7) << 3)] = f2b(fmaxf(acc[nb][r], 0.f));
        }

    // ---- Layer 3 (no relu) ----
#pragma unroll
    for (int nb = 0; nb < 8; ++nb) {
        const float bv = ub3[nb * 16 + lr];
        acc[nb] = (f32x4){bv, bv, bv, bv};
    }
#pragma unroll
    for (int kb = 0; kb < 4; ++kb) {
        const bf16x8 af = ldfrag(&s_h[(myrow * 128 + kb * 32 + lg * 8) ^ asw]);
#pragma unroll
        for (int nb = 0; nb < 8; ++nb)
            acc[nb] = MFMA(af, ldfrag(&u3f[(size_t)((kb * 8 + nb) * 64 + l) * 8]), acc[nb]);
    }
#pragma unroll
    for (int nb = 0; nb < 8; ++nb)
#pragma unroll
        for (int r = 0; r < 4; ++r)
            out[(size_t)(n0blk + w * 16 + lg * 4 + r) * NDIM + nb * 16 + lr] = f2b(acc[nb][r]);
}

// ---------------------------------------------------------------------------
// gate + per-graph reduction (VALU, bf16 node states)
// ---------------------------------------------------------------------------
#define GPB 8
__global__ __launch_bounds__(128) void gate_kernel(
    const unsigned short* __restrict__ ns, const float* __restrict__ gw,
    const float* __restrict__ gb, float* __restrict__ gs)
{
    __shared__ float s_x[GPB][NDIM];
    const int j = threadIdx.x;
    const int n0 = blockIdx.x * GPB;
#pragma unroll
    for (int r = 0; r < GPB; ++r)
        s_x[r][j] = b2f(ns[(size_t)(n0 + r) * NDIM + j]);
    __syncthreads();

    float acc[GPB];
    const float bb = gb[j];
#pragma unroll
    for (int r = 0; r < GPB; ++r) acc[r] = bb;
    for (int i = 0; i < NDIM; i += 4) {
        const float w0 = gw[(i + 0) * NDIM + j];
        const float w1 = gw[(i + 1) * NDIM + j];
        const float wv2 = gw[(i + 2) * NDIM + j];
        const float wv3 = gw[(i + 3) * NDIM + j];
#pragma unroll
        for (int r = 0; r < GPB; ++r) {
            const float4 x = *(const float4*)&s_x[r][i];
            acc[r] = fmaf(x.x, w0, acc[r]);
            acc[r] = fmaf(x.y, w1, acc[r]);
            acc[r] = fmaf(x.z, wv2, acc[r]);
            acc[r] = fmaf(x.w, wv3, acc[r]);
        }
    }
    float part = 0.f;
#pragma unroll
    for (int r = 0; r < GPB; ++r) {
        const float g = 1.f / (1.f + expf(-acc[r]));
        part += s_x[r][j] * g;
    }
    atomicAdd(&gs[(n0 >> 12) * NDIM + j], part);
}

// ---------------------------------------------------------------------------
// final: out = relu(gs @ agg_w1 + ab1) @ agg_w2 + ab2    (16x128 -> 16x128)
// ---------------------------------------------------------------------------
__global__ __launch_bounds__(256) void final_kernel(
    const float* __restrict__ gs,
    const float* __restrict__ aw1, const float* __restrict__ ab1,
    const float* __restrict__ aw2, const float* __restrict__ ab2,
    float* __restrict__ out)
{
    __shared__ float s_g[16 * 128];
    __shared__ float s_h[16 * 256];
    const int t = threadIdx.x;
    for (int k = t; k < 16 * 128; k += 256) s_g[k] = gs[k];
    __syncthreads();
    for (int r = 0; r < 16; ++r) {
        float a = ab1[t];
        for (int i = 0; i < 128; ++i)
            a = fmaf(s_g[r * 128 + i], aw1[i * 256 + t], a);
        s_h[r * 256 + t] = fmaxf(a, 0.f);
    }
    __syncthreads();
    for (int k = t; k < 16 * 128; k += 256) {
        const int r = k >> 7, j = k & 127;
        float a = ab2[j];
        for (int i = 0; i < 256; ++i)
            a = fmaf(s_h[r * 256 + i], aw2[i * 128 + j], a);
        out[k] = a;
    }
}

// ---------------------------------------------------------------------------
extern "C" void kernel_launch(void* const* d_in, const int* in_sizes, int n_in,
                              void* d_out, int out_size, void* d_ws, size_t ws_size,
                              hipStream_t stream)
{
    const float* nf      = (const float*)d_in[0];
    const float* ef      = (const float*)d_in[1];
    const int*   ev      = (const int*)d_in[2];
    const float* msg_w1  = (const float*)d_in[3];
    const float* msg_b1  = (const float*)d_in[4];
    const float* msg_w2  = (const float*)d_in[5];
    const float* msg_b2  = (const float*)d_in[6];
    const float* msg_w3  = (const float*)d_in[7];
    const float* msg_b3  = (const float*)d_in[8];
    const float* upd_w1  = (const float*)d_in[9];
    const float* upd_b1  = (const float*)d_in[10];
    const float* upd_w2  = (const float*)d_in[11];
    const float* upd_b2  = (const float*)d_in[12];
    const float* upd_w3  = (const float*)d_in[13];
    const float* upd_b3  = (const float*)d_in[14];
    const float* gate_w  = (const float*)d_in[15];
    const float* gate_b  = (const float*)d_in[16];
    const float* agg_w1  = (const float*)d_in[17];
    const float* agg_b1  = (const float*)d_in[18];
    const float* agg_w2  = (const float*)d_in[19];
    const float* agg_b2  = (const float*)d_in[20];

    const size_t NS = (size_t)TOTAL * NDIM;
    unsigned short* ns0 = (unsigned short*)d_ws;
    unsigned short* nsA = ns0 + NS;
    unsigned short* nsB = nsA + NS;
    float* summed = (float*)(nsB + NS);
    float* gs     = summed + NS;
    unsigned short* w1f = (unsigned short*)(gs + 16 * NDIM);   // 10*4096
    unsigned short* w2f = w1f + 10 * 4096;                     // 4*4096
    unsigned short* w3f = w2f + 4 * 4096;
    unsigned short* u1f = w3f + 4 * 4096;                      // 12*4096
    unsigned short* u2f = u1f + 12 * 4096;
    unsigned short* u3f = u2f + 4 * 4096;
    unsigned short* efp = u3f + 4 * 4096;                      // E*64

    cvt_kernel<<<(int)(NS / 4 + 255) / 256, 256, 0, stream>>>(nf, ns0, (int)(NS / 4));
    pkw_kernel<<<10 * 16, 256, 0, stream>>>(msg_w1, w1f, 10);
    pkw_kernel<<< 4 * 16, 256, 0, stream>>>(msg_w2, w2f, 4);
    pkw_kernel<<< 4 * 16, 256, 0, stream>>>(msg_w3, w3f, 4);
    pkw_kernel<<<12 * 16, 256, 0, stream>>>(upd_w1, u1f, 12);
    pkw_kernel<<< 4 * 16, 256, 0, stream>>>(upd_w2, u2f, 4);
    pkw_kernel<<< 4 * 16, 256, 0, stream>>>(upd_w3, u3f, 4);
    pkef_kernel<<<(int)((size_t)NEDGE * EDIM / 256), 256, 0, stream>>>(ef, efp);

    const unsigned short* curs[3] = { ns0, nsA, nsB };
    unsigned short* nxts[3]       = { nsA, nsB, nsA };
    for (int lyr = 0; lyr < 3; ++lyr) {
        hipMemsetAsync(summed, 0, NS * sizeof(float), stream);
        edge_mfma<<<NEDGE / 128, 256, 0, stream>>>(curs[lyr], efp, ev, w1f, w2f, w3f,
                                                   msg_b1, msg_b2, msg_b3, summed);
        upd_mfma<<<TOTAL / 64, 256, 0, stream>>>(curs[lyr], summed, u1f, u2f, u3f,
                                                 upd_b1, upd_b2, upd_b3, nxts[lyr]);
    }
    hipMemsetAsync(gs, 0, (size_t)16 * NDIM * sizeof(float), stream);
    gate_kernel<<<TOTAL / GPB, 128, 0, stream>>>(nsA, gate_w, gate_b, gs);
    final_kernel<<<1, 256, 0, stream>>>(gs, agg_w1, agg_b1, agg_w2, agg_b2,
                                        (float*)d_out);
}

// Round 8
// 1799.961 us; speedup vs baseline: 1.4374x; 1.1782x over previous
//
#include <hip/hip_runtime.h>
#include <math.h>

#define TOTAL  65536      // B*2*N nodes
#define NDIM   128        // D
#define NEDGE  524288     // E
#define EDIM   64         // ED

typedef __bf16 bf16x8 __attribute__((ext_vector_type(8)));
typedef float  f32x4  __attribute__((ext_vector_type(4)));
typedef unsigned int u32x4 __attribute__((ext_vector_type(4)));
typedef unsigned short u16x8 __attribute__((ext_vector_type(8)));

#define MFMA(a, b, c) __builtin_amdgcn_mfma_f32_16x16x32_bf16((a), (b), (c), 0, 0, 0)

static __device__ __forceinline__ float b2f(unsigned short u) {
    union { float f; unsigned int i; } v; v.i = ((unsigned int)u) << 16; return v.f;
}
static __device__ __forceinline__ unsigned short f2b(float f) {  // RNE
    union { float f; unsigned int i; } v; v.f = f;
    unsigned int r = v.i + 0x7FFFu + ((v.i >> 16) & 1u);
    return (unsigned short)(r >> 16);
}
static __device__ __forceinline__ bf16x8 ldfrag(const unsigned short* p) {
    return __builtin_bit_cast(bf16x8, *(const u32x4*)p);
}
static __device__ __forceinline__ bf16x8 packf8(float4 a, float4 b) {
    u32x4 u;
    u[0] = (unsigned int)f2b(a.x) | ((unsigned int)f2b(a.y) << 16);
    u[1] = (unsigned int)f2b(a.z) | ((unsigned int)f2b(a.w) << 16);
    u[2] = (unsigned int)f2b(b.x) | ((unsigned int)f2b(b.y) << 16);
    u[3] = (unsigned int)f2b(b.z) | ((unsigned int)f2b(b.w) << 16);
    return __builtin_bit_cast(bf16x8, u);
}

// ---------------------------------------------------------------------------
__global__ __launch_bounds__(256) void cvt_kernel(
    const float* __restrict__ in, unsigned short* __restrict__ out, int n4)
{
    int i = blockIdx.x * 256 + threadIdx.x;
    if (i < n4) {
        float4 x = *(const float4*)&in[(size_t)i * 4];
        out[(size_t)i * 4 + 0] = f2b(x.x);
        out[(size_t)i * 4 + 1] = f2b(x.y);
        out[(size_t)i * 4 + 2] = f2b(x.z);
        out[(size_t)i * 4 + 3] = f2b(x.w);
    }
}

// pack fp32 weight [K][128] -> frag-major bf16 [KB][8][64][8]
__global__ __launch_bounds__(256) void pkw_kernel(
    const float* __restrict__ src, unsigned short* __restrict__ dst, int KB)
{
    int idx = blockIdx.x * 256 + threadIdx.x;
    if (idx >= KB * 4096) return;
    const int j  = idx & 7;
    const int l  = (idx >> 3) & 63;
    const int nb = (idx >> 9) & 7;
    const int kb = idx >> 12;
    const int k   = kb * 32 + (l >> 4) * 8 + j;
    const int col = nb * 16 + (l & 15);
    dst[idx] = f2b(src[(size_t)k * 128 + col]);
}

// pack edge features fp32 [E][64] -> bf16 frag-major
__global__ __launch_bounds__(256) void pkef_kernel(
    const float* __restrict__ ef, unsigned short* __restrict__ out)
{
    const size_t idx = (size_t)blockIdx.x * 256 + threadIdx.x;  // < E*64
    const int j  = (int)(idx & 7);
    const int l  = (int)((idx >> 3) & 63);
    const int kb = (int)((idx >> 9) & 1);
    const int rt = (int)((idx >> 10) & 1);
    const int w  = (int)((idx >> 11) & 3);
    const size_t blk = idx >> 13;
    const size_t e = blk * 128 + w * 32 + rt * 16 + (l & 15);
    const int col = kb * 32 + (l >> 4) * 8 + j;
    out[idx] = f2b(ef[e * 64 + col]);
}

// ---------------------------------------------------------------------------
// CSR build (once per call): hist -> scan -> fill
// ---------------------------------------------------------------------------
__global__ __launch_bounds__(256) void hist_kernel(
    const int* __restrict__ ev, unsigned int* __restrict__ cnt)
{
    const int t = blockIdx.x * 256 + threadIdx.x;   // < 2E
    atomicAdd(&cnt[ev[t]], 1u);
}

__global__ __launch_bounds__(1024) void scan_kernel(
    const unsigned int* __restrict__ cnt, unsigned int* __restrict__ rowptr,
    unsigned int* __restrict__ cursor)
{
    __shared__ unsigned int part[1024];
    const int t = threadIdx.x;
    unsigned int s = 0;
    for (int j = 0; j < 64; ++j) s += cnt[t * 64 + j];
    part[t] = s;
    __syncthreads();
    for (int off = 1; off < 1024; off <<= 1) {
        unsigned int v = (t >= off) ? part[t - off] : 0u;
        __syncthreads();
        part[t] += v;
        __syncthreads();
    }
    unsigned int run = (t == 0) ? 0u : part[t - 1];
    for (int j = 0; j < 64; ++j) {
        rowptr[t * 64 + j] = run;
        cursor[t * 64 + j] = run;
        run += cnt[t * 64 + j];
    }
    if (t == 1023) rowptr[65536] = part[1023];
}

__global__ __launch_bounds__(256) void fill_kernel(
    const int* __restrict__ ev, unsigned int* __restrict__ cursor,
    unsigned int* __restrict__ eidx)
{
    const int e = blockIdx.x * 256 + threadIdx.x;   // < E
    const int s = ev[2 * e], d = ev[2 * e + 1];
    unsigned int p = atomicAdd(&cursor[s], 1u); eidx[p] = (unsigned int)e;
    unsigned int q = atomicAdd(&cursor[d], 1u); eidx[q] = (unsigned int)e;
}

// ---------------------------------------------------------------------------
// edge (MFMA): A = [ns[src] | ns[dst] | ef] (K=320), 3-layer MLP -> msg bf16
// Block = 128 edges, 4 waves; wave w owns 32 edges. No atomics: coalesced
// msg write through LDS. EFP: packed ef (1) or on-the-fly pack (0).
// ---------------------------------------------------------------------------
template<int EFP>
__global__ __launch_bounds__(256) void edge_mfma(
    const unsigned short* __restrict__ ns,
    const unsigned short* __restrict__ efp, const float* __restrict__ ef,
    const int* __restrict__ ev,
    const unsigned short* __restrict__ w1f,  // [10][8][64][8]
    const unsigned short* __restrict__ w2f,  // [4][8][64][8]
    const unsigned short* __restrict__ w3f,  // [4][8][64][8]
    const float* __restrict__ b1, const float* __restrict__ b2,
    const float* __restrict__ b3, unsigned short* __restrict__ msg)
{
    __shared__ unsigned short s_h[128 * 128];  // 32 KB, reused across layers
    __shared__ int s_src[128], s_dst[128];

    const int tid = threadIdx.x;
    const int w = tid >> 6, l = tid & 63;
    const int lr = l & 15, lg = l >> 4;
    const size_t eblk = (size_t)blockIdx.x * 128;

    {
        const int v = ev[eblk * 2 + tid];
        if (tid & 1) s_dst[tid >> 1] = v; else s_src[tid >> 1] = v;
    }
    __syncthreads();

    const int row0 = w * 32 + lr;      // A-row, tile rt=0
    const int row1 = row0 + 16;        // rt=1
    const int ms0 = s_src[row0], ms1 = s_src[row1];
    const int md0 = s_dst[row0], md1 = s_dst[row1];

    f32x4 acc0[8], acc1[8];
#pragma unroll
    for (int nb = 0; nb < 8; ++nb) {
        const float bv = b1[nb * 16 + lr];
        acc0[nb] = (f32x4){bv, bv, bv, bv};
        acc1[nb] = acc0[nb];
    }
    // ---- L1 seg0: ns[src], k=0..127 ----
#pragma unroll
    for (int kb = 0; kb < 4; ++kb) {
        const bf16x8 a0 = ldfrag(&ns[(size_t)ms0 * 128 + kb * 32 + lg * 8]);
        const bf16x8 a1 = ldfrag(&ns[(size_t)ms1 * 128 + kb * 32 + lg * 8]);
#pragma unroll
        for (int nb = 0; nb < 8; ++nb) {
            const bf16x8 bfr = ldfrag(&w1f[(size_t)((kb * 8 + nb) * 64 + l) * 8]);
            acc0[nb] = MFMA(a0, bfr, acc0[nb]);
            acc1[nb] = MFMA(a1, bfr, acc1[nb]);
        }
    }
    // ---- L1 seg1: ns[dst], k=128..255 ----
#pragma unroll
    for (int kb = 0; kb < 4; ++kb) {
        const bf16x8 a0 = ldfrag(&ns[(size_t)md0 * 128 + kb * 32 + lg * 8]);
        const bf16x8 a1 = ldfrag(&ns[(size_t)md1 * 128 + kb * 32 + lg * 8]);
#pragma unroll
        for (int nb = 0; nb < 8; ++nb) {
            const bf16x8 bfr = ldfrag(&w1f[(size_t)(((kb + 4) * 8 + nb) * 64 + l) * 8]);
            acc0[nb] = MFMA(a0, bfr, acc0[nb]);
            acc1[nb] = MFMA(a1, bfr, acc1[nb]);
        }
    }
    // ---- L1 seg2: ef, k=256..319 ----
#pragma unroll
    for (int kb = 0; kb < 2; ++kb) {
        bf16x8 a0, a1;
        if (EFP) {
            const size_t eb = (((size_t)blockIdx.x * 4 + w) * 4 + kb) * 512 + l * 8;
            a0 = ldfrag(&efp[eb]);
            a1 = ldfrag(&efp[eb + 1024]);
        } else {
            const size_t er0 = eblk + row0, er1 = eblk + row1;
            a0 = packf8(*(const float4*)&ef[er0 * EDIM + kb * 32 + lg * 8],
                        *(const float4*)&ef[er0 * EDIM + kb * 32 + lg * 8 + 4]);
            a1 = packf8(*(const float4*)&ef[er1 * EDIM + kb * 32 + lg * 8],
                        *(const float4*)&ef[er1 * EDIM + kb * 32 + lg * 8 + 4]);
        }
#pragma unroll
        for (int nb = 0; nb < 8; ++nb) {
            const bf16x8 bfr = ldfrag(&w1f[(size_t)(((kb + 8) * 8 + nb) * 64 + l) * 8]);
            acc0[nb] = MFMA(a0, bfr, acc0[nb]);
            acc1[nb] = MFMA(a1, bfr, acc1[nb]);
        }
    }
    // relu -> s_h (wave-private rows, XOR swizzle)
#pragma unroll
    for (int nb = 0; nb < 8; ++nb)
#pragma unroll
        for (int r = 0; r < 4; ++r) {
            const int ra = w * 32 + lg * 4 + r, rb = ra + 16;
            s_h[(ra * 128 + nb * 16 + lr) ^ ((ra & 7) << 3)] = f2b(fmaxf(acc0[nb][r], 0.f));
            s_h[(rb * 128 + nb * 16 + lr) ^ ((rb & 7) << 3)] = f2b(fmaxf(acc1[nb][r], 0.f));
        }

    const int sw0 = (row0 & 7) << 3, sw1 = (row1 & 7) << 3;
    // ---- Layer 2 ----
#pragma unroll
    for (int nb = 0; nb < 8; ++nb) {
        const float bv = b2[nb * 16 + lr];
        acc0[nb] = (f32x4){bv, bv, bv, bv};
        acc1[nb] = acc0[nb];
    }
#pragma unroll
    for (int kb = 0; kb < 4; ++kb) {
        const bf16x8 a0 = ldfrag(&s_h[(row0 * 128 + kb * 32 + lg * 8) ^ sw0]);
        const bf16x8 a1 = ldfrag(&s_h[(row1 * 128 + kb * 32 + lg * 8) ^ sw1]);
#pragma unroll
        for (int nb = 0; nb < 8; ++nb) {
            const bf16x8 bfr = ldfrag(&w2f[(size_t)((kb * 8 + nb) * 64 + l) * 8]);
            acc0[nb] = MFMA(a0, bfr, acc0[nb]);
            acc1[nb] = MFMA(a1, bfr, acc1[nb]);
        }
    }
#pragma unroll
    for (int nb = 0; nb < 8; ++nb)
#pragma unroll
        for (int r = 0; r < 4; ++r) {
            const int ra = w * 32 + lg * 4 + r, rb = ra + 16;
            s_h[(ra * 128 + nb * 16 + lr) ^ ((ra & 7) << 3)] = f2b(fmaxf(acc0[nb][r], 0.f));
            s_h[(rb * 128 + nb * 16 + lr) ^ ((rb & 7) << 3)] = f2b(fmaxf(acc1[nb][r], 0.f));
        }

    // ---- Layer 3 (no relu) ----
#pragma unroll
    for (int nb = 0; nb < 8; ++nb) {
        const float bv = b3[nb * 16 + lr];
        acc0[nb] = (f32x4){bv, bv, bv, bv};
        acc1[nb] = acc0[nb];
    }
#pragma unroll
    for (int kb = 0; kb < 4; ++kb) {
        const bf16x8 a0 = ldfrag(&s_h[(row0 * 128 + kb * 32 + lg * 8) ^ sw0]);
        const bf16x8 a1 = ldfrag(&s_h[(row1 * 128 + kb * 32 + lg * 8) ^ sw1]);
#pragma unroll
        for (int nb = 0; nb < 8; ++nb) {
            const bf16x8 bfr = ldfrag(&w3f[(size_t)((kb * 8 + nb) * 64 + l) * 8]);
            acc0[nb] = MFMA(a0, bfr, acc0[nb]);
            acc1[nb] = MFMA(a1, bfr, acc1[nb]);
        }
    }
    // store L3 output to s_h (swizzled), then coalesced copy to msg
#pragma unroll
    for (int nb = 0; nb < 8; ++nb)
#pragma unroll
        for (int r = 0; r < 4; ++r) {
            const int ra = w * 32 + lg * 4 + r, rb = ra + 16;
            s_h[(ra * 128 + nb * 16 + lr) ^ ((ra & 7) << 3)] = f2b(acc0[nb][r]);
            s_h[(rb * 128 + nb * 16 + lr) ^ ((rb & 7) << 3)] = f2b(acc1[nb][r]);
        }
#pragma unroll
    for (int it = 0; it < 8; ++it) {
        const int row = w * 32 + it * 4 + lg;
        const int sw = (row & 7) << 3;
        const u32x4 v = *(const u32x4*)&s_h[(row * 128 + lr * 8) ^ sw];
        *(u32x4*)&msg[(eblk + row) * 128 + lr * 8] = v;
    }
}

// ---------------------------------------------------------------------------
// gather: summed_bf16[n] = sum of msg rows of incident edges (CSR walk)
// Block = 256 (4 waves), 2 nodes per wave; 256 B coalesced row reads.
// ---------------------------------------------------------------------------
__global__ __launch_bounds__(256) void gather_kernel(
    const unsigned short* __restrict__ msg, const unsigned int* __restrict__ rowptr,
    const unsigned int* __restrict__ eidx, unsigned short* __restrict__ sumb)
{
    const int w = threadIdx.x >> 6, l = threadIdx.x & 63;
#pragma unroll
    for (int i = 0; i < 2; ++i) {
        const int n = blockIdx.x * 8 + w * 2 + i;
        const unsigned int beg = rowptr[n], end = rowptr[n + 1];
        float s0 = 0.f, s1 = 0.f;
        for (unsigned int p = beg; p < end; ++p) {
            const unsigned int e = eidx[p];
            const unsigned int v = *(const unsigned int*)&msg[(size_t)e * 128 + l * 2];
            s0 += b2f((unsigned short)(v & 0xffffu));
            s1 += b2f((unsigned short)(v >> 16));
        }
        const unsigned int o = (unsigned int)f2b(s0) | ((unsigned int)f2b(s1) << 16);
        *(unsigned int*)&sumb[(size_t)n * 128 + l * 2] = o;
    }
}

// ---------------------------------------------------------------------------
// upd (MFMA): A = [ns, summed_bf, ns - partner] (K=384); 64 nodes/block.
// ---------------------------------------------------------------------------
__global__ __launch_bounds__(256) void upd_mfma(
    const unsigned short* __restrict__ ns, const unsigned short* __restrict__ sumb,
    const unsigned short* __restrict__ u1f,  // [12][8][64][8]
    const unsigned short* __restrict__ u2f, const unsigned short* __restrict__ u3f,
    const float* __restrict__ ub1, const float* __restrict__ ub2,
    const float* __restrict__ ub3, unsigned short* __restrict__ out)
{
    __shared__ unsigned short s_h[64 * 128];  // 16 KB, reused

    const int tid = threadIdx.x;
    const int w = tid >> 6, l = tid & 63;
    const int lr = l & 15, lg = l >> 4;
    const int n0blk = blockIdx.x * 64;
    const int node = n0blk + w * 16 + lr;
    const int partner = node ^ 4096;

    bf16x8 nsf[4];
#pragma unroll
    for (int kb = 0; kb < 4; ++kb)
        nsf[kb] = ldfrag(&ns[(size_t)node * 128 + kb * 32 + lg * 8]);

    f32x4 acc[8];
#pragma unroll
    for (int nb = 0; nb < 8; ++nb) {
        const float bv = ub1[nb * 16 + lr];
        acc[nb] = (f32x4){bv, bv, bv, bv};
    }
    // seg0: ns
#pragma unroll
    for (int kb = 0; kb < 4; ++kb) {
#pragma unroll
        for (int nb = 0; nb < 8; ++nb)
            acc[nb] = MFMA(nsf[kb], ldfrag(&u1f[(size_t)((kb * 8 + nb) * 64 + l) * 8]), acc[nb]);
    }
    // seg1: summed (bf16 direct)
#pragma unroll
    for (int kb = 0; kb < 4; ++kb) {
        const bf16x8 af = ldfrag(&sumb[(size_t)node * 128 + kb * 32 + lg * 8]);
#pragma unroll
        for (int nb = 0; nb < 8; ++nb)
            acc[nb] = MFMA(af, ldfrag(&u1f[(size_t)(((kb + 4) * 8 + nb) * 64 + l) * 8]), acc[nb]);
    }
    // seg2: att = ns - ns[partner]
#pragma unroll
    for (int kb = 0; kb < 4; ++kb) {
        const u16x8 a = __builtin_bit_cast(u16x8, nsf[kb]);
        const u16x8 p = __builtin_bit_cast(u16x8, ldfrag(&ns[(size_t)partner * 128 + kb * 32 + lg * 8]));
        u16x8 o;
#pragma unroll
        for (int i = 0; i < 8; ++i) o[i] = f2b(b2f(a[i]) - b2f(p[i]));
        const bf16x8 af = __builtin_bit_cast(bf16x8, o);
#pragma unroll
        for (int nb = 0; nb < 8; ++nb)
            acc[nb] = MFMA(af, ldfrag(&u1f[(size_t)(((kb + 8) * 8 + nb) * 64 + l) * 8]), acc[nb]);
    }
#pragma unroll
    for (int nb = 0; nb < 8; ++nb)
#pragma unroll
        for (int r = 0; r < 4; ++r) {
            const int row = w * 16 + lg * 4 + r;
            s_h[(row * 128 + nb * 16 + lr) ^ ((row & 7) << 3)] = f2b(fmaxf(acc[nb][r], 0.f));
        }

    // ---- Layer 2 ----
    const int myrow = w * 16 + lr;
    const int asw = (myrow & 7) << 3;
#pragma unroll
    for (int nb = 0; nb < 8; ++nb) {
        const float bv = ub2[nb * 16 + lr];
        acc[nb] = (f32x4){bv, bv, bv, bv};
    }
#pragma unroll
    for (int kb = 0; kb < 4; ++kb) {
        const bf16x8 af = ldfrag(&s_h[(myrow * 128 + kb * 32 + lg * 8) ^ asw]);
#pragma unroll
        for (int nb = 0; nb < 8; ++nb)
            acc[nb] = MFMA(af, ldfrag(&u2f[(size_t)((kb * 8 + nb) * 64 + l) * 8]), acc[nb]);
    }
#pragma unroll
    for (int nb = 0; nb < 8; ++nb)
#pragma unroll
        for (int r = 0; r < 4; ++r) {
            const int row = w * 16 + lg * 4 + r;
            s_h[(row * 128 + nb * 16 + lr) ^ ((row & 7) << 3)] = f2b(fmaxf(acc[nb][r], 0.f));
        }

    // ---- Layer 3 (no relu) ----
#pragma unroll
    for (int nb = 0; nb < 8; ++nb) {
        const float bv = ub3[nb * 16 + lr];
        acc[nb] = (f32x4){bv, bv, bv, bv};
    }
#pragma unroll
    for (int kb = 0; kb < 4; ++kb) {
        const bf16x8 af = ldfrag(&s_h[(myrow * 128 + kb * 32 + lg * 8) ^ asw]);
#pragma unroll
        for (int nb = 0; nb < 8; ++nb)
            acc[nb] = MFMA(af, ldfrag(&u3f[(size_t)((kb * 8 + nb) * 64 + l) * 8]), acc[nb]);
    }
#pragma unroll
    for (int nb = 0; nb < 8; ++nb)
#pragma unroll
        for (int r = 0; r < 4; ++r)
            out[(size_t)(n0blk + w * 16 + lg * 4 + r) * NDIM + nb * 16 + lr] = f2b(acc[nb][r]);
}

// ---------------------------------------------------------------------------
#define GPB 8
__global__ __launch_bounds__(128) void gate_kernel(
    const unsigned short* __restrict__ ns, const float* __restrict__ gw,
    const float* __restrict__ gb, float* __restrict__ gs)
{
    __shared__ float s_x[GPB][NDIM];
    const int j = threadIdx.x;
    const int n0 = blockIdx.x * GPB;
#pragma unroll
    for (int r = 0; r < GPB; ++r)
        s_x[r][j] = b2f(ns[(size_t)(n0 + r) * NDIM + j]);
    __syncthreads();

    float acc[GPB];
    const float bb = gb[j];
#pragma unroll
    for (int r = 0; r < GPB; ++r) acc[r] = bb;
    for (int i = 0; i < NDIM; i += 4) {
        const float w0 = gw[(i + 0) * NDIM + j];
        const float w1 = gw[(i + 1) * NDIM + j];
        const float wv2 = gw[(i + 2) * NDIM + j];
        const float wv3 = gw[(i + 3) * NDIM + j];
#pragma unroll
        for (int r = 0; r < GPB; ++r) {
            const float4 x = *(const float4*)&s_x[r][i];
            acc[r] = fmaf(x.x, w0, acc[r]);
            acc[r] = fmaf(x.y, w1, acc[r]);
            acc[r] = fmaf(x.z, wv2, acc[r]);
            acc[r] = fmaf(x.w, wv3, acc[r]);
        }
    }
    float part = 0.f;
#pragma unroll
    for (int r = 0; r < GPB; ++r) {
        const float g = 1.f / (1.f + expf(-acc[r]));
        part += s_x[r][j] * g;
    }
    atomicAdd(&gs[(n0 >> 12) * NDIM + j], part);
}

// ---------------------------------------------------------------------------
__global__ __launch_bounds__(256) void final_kernel(
    const float* __restrict__ gs,
    const float* __restrict__ aw1, const float* __restrict__ ab1,
    const float* __restrict__ aw2, const float* __restrict__ ab2,
    float* __restrict__ out)
{
    __shared__ float s_g[16 * 128];
    __shared__ float s_h[16 * 256];
    const int t = threadIdx.x;
    for (int k = t; k < 16 * 128; k += 256) s_g[k] = gs[k];
    __syncthreads();
    for (int r = 0; r < 16; ++r) {
        float a = ab1[t];
        for (int i = 0; i < 128; ++i)
            a = fmaf(s_g[r * 128 + i], aw1[i * 256 + t], a);
        s_h[r * 256 + t] = fmaxf(a, 0.f);
    }
    __syncthreads();
    for (int k = t; k < 16 * 128; k += 256) {
        const int r = k >> 7, j = k & 127;
        float a = ab2[j];
        for (int i = 0; i < 256; ++i)
            a = fmaf(s_h[r * 256 + i], aw2[i * 128 + j], a);
        out[k] = a;
    }
}

// ---------------------------------------------------------------------------
extern "C" void kernel_launch(void* const* d_in, const int* in_sizes, int n_in,
                              void* d_out, int out_size, void* d_ws, size_t ws_size,
                              hipStream_t stream)
{
    const float* nf      = (const float*)d_in[0];
    const float* ef      = (const float*)d_in[1];
    const int*   ev      = (const int*)d_in[2];
    const float* msg_w1  = (const float*)d_in[3];
    const float* msg_b1  = (const float*)d_in[4];
    const float* msg_w2  = (const float*)d_in[5];
    const float* msg_b2  = (const float*)d_in[6];
    const float* msg_w3  = (const float*)d_in[7];
    const float* msg_b3  = (const float*)d_in[8];
    const float* upd_w1  = (const float*)d_in[9];
    const float* upd_b1  = (const float*)d_in[10];
    const float* upd_w2  = (const float*)d_in[11];
    const float* upd_b2  = (const float*)d_in[12];
    const float* upd_w3  = (const float*)d_in[13];
    const float* upd_b3  = (const float*)d_in[14];
    const float* gate_w  = (const float*)d_in[15];
    const float* gate_b  = (const float*)d_in[16];
    const float* agg_w1  = (const float*)d_in[17];
    const float* agg_b1  = (const float*)d_in[18];
    const float* agg_w2  = (const float*)d_in[19];
    const float* agg_b2  = (const float*)d_in[20];

    const size_t NS = (size_t)TOTAL * NDIM;          // 8388608 elements
    unsigned short* p = (unsigned short*)d_ws;
    unsigned short* ns0 = p;            p += NS;
    unsigned short* nsA = p;            p += NS;
    unsigned short* nsB = p;            p += NS;
    unsigned short* sumb = p;           p += NS;
    unsigned short* w1f = p;            p += 10 * 4096;
    unsigned short* w2f = p;            p += 4 * 4096;
    unsigned short* w3f = p;            p += 4 * 4096;
    unsigned short* u1f = p;            p += 12 * 4096;
    unsigned short* u2f = p;            p += 4 * 4096;
    unsigned short* u3f = p;            p += 4 * 4096;
    float* gs = (float*)p;              p += 2 * 16 * NDIM;       // 2048 f32
    unsigned int* cnt    = (unsigned int*)p;  p += 2 * 65536;
    unsigned int* cursor = (unsigned int*)p;  p += 2 * 65536;
    unsigned int* rowptr = (unsigned int*)p;  p += 2 * 65540;
    unsigned int* eidx   = (unsigned int*)p;  p += 2 * 2 * NEDGE;
    unsigned short* msg  = p;           p += (size_t)NEDGE * 128;
    unsigned short* efp  = p;           p += (size_t)NEDGE * EDIM;

    const size_t need_full = (size_t)(p - (unsigned short*)d_ws) * 2;
    const bool use_efp = ws_size >= need_full;

    cvt_kernel<<<(int)(NS / 4 + 255) / 256, 256, 0, stream>>>(nf, ns0, (int)(NS / 4));
    pkw_kernel<<<10 * 16, 256, 0, stream>>>(msg_w1, w1f, 10);
    pkw_kernel<<< 4 * 16, 256, 0, stream>>>(msg_w2, w2f, 4);
    pkw_kernel<<< 4 * 16, 256, 0, stream>>>(msg_w3, w3f, 4);
    pkw_kernel<<<12 * 16, 256, 0, stream>>>(upd_w1, u1f, 12);
    pkw_kernel<<< 4 * 16, 256, 0, stream>>>(upd_w2, u2f, 4);
    pkw_kernel<<< 4 * 16, 256, 0, stream>>>(upd_w3, u3f, 4);
    if (use_efp)
        pkef_kernel<<<(int)((size_t)NEDGE * EDIM / 256), 256, 0, stream>>>(ef, efp);

    // CSR build (edges constant across layers)
    hipMemsetAsync(cnt, 0, 65536 * sizeof(unsigned int), stream);
    hist_kernel<<<2 * NEDGE / 256, 256, 0, stream>>>(ev, cnt);
    scan_kernel<<<1, 1024, 0, stream>>>(cnt, rowptr, cursor);
    fill_kernel<<<NEDGE / 256, 256, 0, stream>>>(ev, cursor, eidx);

    const unsigned short* curs[3] = { ns0, nsA, nsB };
    unsigned short* nxts[3]       = { nsA, nsB, ns0 };
    for (int lyr = 0; lyr < 3; ++lyr) {
        if (use_efp)
            edge_mfma<1><<<NEDGE / 128, 256, 0, stream>>>(curs[lyr], efp, ef, ev,
                w1f, w2f, w3f, msg_b1, msg_b2, msg_b3, msg);
        else
            edge_mfma<0><<<NEDGE / 128, 256, 0, stream>>>(curs[lyr], efp, ef, ev,
                w1f, w2f, w3f, msg_b1, msg_b2, msg_b3, msg);
        gather_kernel<<<TOTAL / 8, 256, 0, stream>>>(msg, rowptr, eidx, sumb);
        upd_mfma<<<TOTAL / 64, 256, 0, stream>>>(curs[lyr], sumb, u1f, u2f, u3f,
                                                 upd_b1, upd_b2, upd_b3, nxts[lyr]);
    }
    hipMemsetAsync(gs, 0, (size_t)16 * NDIM * sizeof(float), stream);
    gate_kernel<<<TOTAL / GPB, 128, 0, stream>>>(ns0, gate_w, gate_b, gs);
    final_kernel<<<1, 256, 0, stream>>>(gs, agg_w1, agg_b1, agg_w2, agg_b2,
                                        (float*)d_out);
}